// Round 4
// baseline (632.598 us; speedup 1.0000x reference)
//
#include <hip/hip_runtime.h>

// GraphAttentionLayer: B=4, N=4096, F=128, fp32 in/out.
//   w_ij = adj_ij * ( Wh2_j >= -Wh1_i ? P1_i*P2_j : Q1_i*Q2_j )   (softmax scale-invariance
//   + separability of exp(leaky(x+y)) per branch), h = (w @ vp) / rowsum(w), out = leaky(h@Wo^T).
// k_attn v4: BARRIER-FREE K-loop. B-fragments read directly from global (L1/L2-resident vpT
// slice; no LDS staging, no __syncthreads in the loop). M=64/block, 1024 blocks, 4 blocks/CU
// (16 waves/CU) for latency hiding. adj register-prefetched one iteration ahead.

constexpr int B = 4, N = 4096, F = 128;
constexpr int BN = B * N;
constexpr int BK = 64;
constexpr int SPLITS = 4;
constexpr int JC = N / SPLITS;   // 1024 j per block
constexpr int NIT = JC / BK;     // 16 iterations
#define ALPHA 0.1f

using float4v = __attribute__((ext_vector_type(4))) float;
using short8 = __attribute__((ext_vector_type(8))) short;

__device__ __forceinline__ float leaky(float x) { return x >= 0.f ? x : ALPHA * x; }
__device__ __forceinline__ unsigned short f2bf(float x) {  // RNE float->bf16
    unsigned u = __float_as_uint(x);
    u = (u + 0x7FFFu + ((u >> 16) & 1u)) >> 16;
    return (unsigned short)u;
}
// pack two floats -> two RNE bf16 in one dword: {bf(hi)[31:16], bf(lo)[15:0]}
__device__ __forceinline__ unsigned pack_bf2(float lo, float hi) {
    unsigned a = __float_as_uint(lo), b2 = __float_as_uint(hi);
    a = a + 0x7FFFu + ((a >> 16) & 1u);
    b2 = b2 + 0x7FFFu + ((b2 >> 16) & 1u);
    return __builtin_amdgcn_perm(b2, a, 0x07060302u);  // bytes: b2[3],b2[2],a[3],a[2]
}

// ---------------- K0: c1, c2, d1, d2 ----------------
__global__ void k_prep(const float* __restrict__ Wq_w, const float* __restrict__ Wq_b,
                       const float* __restrict__ Wk_w, const float* __restrict__ Wk_b,
                       const float* __restrict__ a, float* __restrict__ c1,
                       float* __restrict__ c2, float* __restrict__ d12) {
    __shared__ float as[2 * F];
    __shared__ float red[2 * F];
    int t = threadIdx.x;  // 256
    as[t] = a[t];
    __syncthreads();
    int f = t & 127;
    const float* W = (t < F) ? Wq_w : Wk_w;
    const float* ao = (t < F) ? as : as + F;
    float s = 0.f;
#pragma unroll 8
    for (int o = 0; o < F; o++) s = fmaf(W[o * F + f], ao[o], s);
    if (t < F) c1[f] = s; else c2[f] = s;
    red[t] = (t < F) ? Wq_b[f] * as[f] : Wk_b[f] * as[F + f];
    __syncthreads();
    for (int st = 64; st > 0; st >>= 1) {
        if (f < st) red[t] += red[t + st];
        __syncthreads();
    }
    if (t == 0) d12[0] = red[0];
    if (t == F) d12[1] = red[F];
}

// ---------------- K1: Wh1, Wh2 ----------------
__global__ void k_wh(const float* __restrict__ q, const float* __restrict__ k,
                     const float* __restrict__ c1, const float* __restrict__ c2,
                     const float* __restrict__ d12,
                     float* __restrict__ Wh1, float* __restrict__ Wh2) {
    __shared__ float c1s[F], c2s[F];
    int t = threadIdx.x;
    if (t < F) c1s[t] = c1[t]; else c2s[t - F] = c2[t - F];
    __syncthreads();
    int row = blockIdx.x * 8 + (t >> 5);
    int lane = t & 31;
    float4 q4 = reinterpret_cast<const float4*>(q)[row * 32 + lane];
    float4 k4 = reinterpret_cast<const float4*>(k)[row * 32 + lane];
    float s1 = q4.x * c1s[lane * 4 + 0] + q4.y * c1s[lane * 4 + 1] +
               q4.z * c1s[lane * 4 + 2] + q4.w * c1s[lane * 4 + 3];
    float s2 = k4.x * c2s[lane * 4 + 0] + k4.y * c2s[lane * 4 + 1] +
               k4.z * c2s[lane * 4 + 2] + k4.w * c2s[lane * 4 + 3];
    for (int m = 16; m > 0; m >>= 1) { s1 += __shfl_xor(s1, m); s2 += __shfl_xor(s2, m); }
    if (lane == 0) { Wh1[row] = s1 + d12[0]; Wh2[row] = s2 + d12[1]; }
}

// ---------------- K1b: per-batch max of Wh2 ----------------
__global__ void k_max2(const float* __restrict__ Wh2, float* __restrict__ M2) {
    int b = blockIdx.x, t = threadIdx.x;
    float m = -1e30f;
    for (int i = t; i < N; i += 256) m = fmaxf(m, Wh2[b * N + i]);
    __shared__ float red[256];
    red[t] = m;
    __syncthreads();
    for (int s = 128; s > 0; s >>= 1) { if (t < s) red[t] = fmaxf(red[t], red[t + s]); __syncthreads(); }
    if (t == 0) M2[b] = red[0];
}

// ---------------- K1c: exp tables ----------------
__global__ void k_tab(const float* __restrict__ Wh1, const float* __restrict__ Wh2,
                      const float* __restrict__ M2,
                      float* __restrict__ P1, float* __restrict__ Q1,
                      float* __restrict__ P2, float* __restrict__ Q2) {
    int i = blockIdx.x * 256 + threadIdx.x;
    int b = i >> 12;  // N = 4096
    float w1 = Wh1[i], w2 = Wh2[i];
    float mi = leaky(w1 + M2[b]);  // per-row shift (cancels in h; range only)
    P1[i] = __expf(w1 - mi);
    Q1[i] = __expf(ALPHA * w1 - mi);
    P2[i] = __expf(w2);
    Q2[i] = __expf(ALPHA * w2);
}

// ---------------- K2: vpT = bf16( (v @ Wv^T + bv)^T ), layout [B][F][N] ----------------
__global__ __launch_bounds__(256) void k_vp(const float* __restrict__ v,
                                            const float* __restrict__ Wv_w,
                                            const float* __restrict__ Wv_b,
                                            unsigned short* __restrict__ vpT) {
    __shared__ float vs[32][F];            // 16 KB
    __shared__ float Ws[F][129];           // 66 KB, pad -> conflict-free column reads
    __shared__ unsigned short ts[F][40];   // 10 KB transpose tile (pad 8)
    int t = threadIdx.x;
    int row0g = blockIdx.x * 32;           // flat row in [0, BN)
    int b = row0g >> 12;
    int row0 = row0g & (N - 1);
    {
        const float4* src = reinterpret_cast<const float4*>(v + row0g * F);
        float4* dst = reinterpret_cast<float4*>(&vs[0][0]);
#pragma unroll
        for (int u = 0; u < 4; u++) dst[u * 256 + t] = src[u * 256 + t];
    }
    {
        const float4* src = reinterpret_cast<const float4*>(Wv_w);
#pragma unroll
        for (int u = 0; u < 16; u++) {
            int unit = u * 256 + t;
            int r = unit >> 5, s = unit & 31;
            float4 val = src[unit];
            Ws[r][s * 4 + 0] = val.x; Ws[r][s * 4 + 1] = val.y;
            Ws[r][s * 4 + 2] = val.z; Ws[r][s * 4 + 3] = val.w;
        }
    }
    int f = t & 127, g = t >> 7;
    float bias = Wv_b[f];
    __syncthreads();
    float acc[16];
#pragma unroll
    for (int r = 0; r < 16; r++) acc[r] = bias;
    for (int kk = 0; kk < F; kk++) {
        float wk = Ws[f][kk];
#pragma unroll
        for (int r = 0; r < 16; r++) acc[r] = fmaf(vs[g * 16 + r][kk], wk, acc[r]);
    }
#pragma unroll
    for (int r = 0; r < 16; r++) ts[f][g * 16 + r] = f2bf(acc[r]);
    __syncthreads();
    int fr = t >> 1, hseg = t & 1;
    uint4 d0 = *reinterpret_cast<uint4*>(&ts[fr][hseg * 16]);
    uint4 d1 = *reinterpret_cast<uint4*>(&ts[fr][hseg * 16 + 8]);
    unsigned short* dst = vpT + ((size_t)(b * F + fr) * N + row0 + hseg * 16);
    *reinterpret_cast<uint4*>(dst) = d0;
    *reinterpret_cast<uint4*>(dst + 8) = d1;
}

// ---------------- K3: MFMA attention, barrier-free K-loop, B-frags from global ----------------
__global__ __launch_bounds__(256, 4) void k_attn(
    const unsigned short* __restrict__ vpT, const int* __restrict__ adj,
    const float* __restrict__ Wh1, const float* __restrict__ P1, const float* __restrict__ Q1,
    const float* __restrict__ P2, const float* __restrict__ Q2, const float* __restrict__ Wh2,
    float* __restrict__ h_part, float* __restrict__ den_part) {
    __shared__ __align__(16) float sP2[JC], sQ2[JC], sW2[JC];  // 12 KB total
    int t = threadIdx.x;
    int idx = blockIdx.x;            // 1024 = B * 64 tiles * 4 splits
    int split = idx & 3;
    int tile = (idx >> 2) & 63;
    int b = idx >> 8;
    int i0 = tile * 64;
    int jb0 = split * JC;
    int widx = t >> 6, lane = t & 63, m = lane & 15, q = lane >> 4;

    {  // preload P2/Q2/W2 for the whole j-slice (1024 floats each) — only LDS use
        reinterpret_cast<float4*>(sP2)[t] = reinterpret_cast<const float4*>(P2 + b * N + jb0)[t];
        reinterpret_cast<float4*>(sQ2)[t] = reinterpret_cast<const float4*>(Q2 + b * N + jb0)[t];
        reinterpret_cast<float4*>(sW2)[t] = reinterpret_cast<const float4*>(Wh2 + b * N + jb0)[t];
    }

    int gi = b * N + i0 + widx * 16 + m;   // this lane's A-row (1 row-tile per wave)
    float p1 = P1[gi], q1 = Q1[gi], t1 = -Wh1[gi];

    // per-lane B pointer: feature row m (n-index), k-offset q*8; +nt*16*N per n-tile
    const unsigned short* vbl = vpT + (size_t)b * F * N + (size_t)m * N + jb0 + q * 8;
    const int* adjr = adj + (size_t)gi * N + jb0 + q * 8;   // + it*64 + kh*32 (+0/+4)

    __syncthreads();   // tables ready; no barriers after this point

    int4 aregA[4], aregB[4];   // [kh*2 + half]: 8 adj ints per lane per iter

    auto load_adj = [&](int it, int4* ar) {
#pragma unroll
        for (int kh = 0; kh < 2; kh++) {
            const int* p = adjr + it * BK + kh * 32;
            ar[kh * 2 + 0] = *reinterpret_cast<const int4*>(p);
            ar[kh * 2 + 1] = *reinterpret_cast<const int4*>(p + 4);
        }
    };

    float4v acc[8];
#pragma unroll
    for (int nt = 0; nt < 8; nt++) acc[nt] = (float4v){0.f, 0.f, 0.f, 0.f};
    float den = 0.f;

    // w-gen: 8 masked-selected weights -> bf16 A-frag
    auto gen_af = [&](const int4& a0, const int4& a1, const float4& x2a, const float4& x2b,
                      const float4& p2a, const float4& p2b, const float4& q2a,
                      const float4& q2b, float& dn) -> short8 {
        float w0 = a0.x ? ((x2a.x >= t1) ? p1 * p2a.x : q1 * q2a.x) : 0.f;
        float w1 = a0.y ? ((x2a.y >= t1) ? p1 * p2a.y : q1 * q2a.y) : 0.f;
        float w2 = a0.z ? ((x2a.z >= t1) ? p1 * p2a.z : q1 * q2a.z) : 0.f;
        float w3 = a0.w ? ((x2a.w >= t1) ? p1 * p2a.w : q1 * q2a.w) : 0.f;
        float w4 = a1.x ? ((x2b.x >= t1) ? p1 * p2b.x : q1 * q2b.x) : 0.f;
        float w5 = a1.y ? ((x2b.y >= t1) ? p1 * p2b.y : q1 * q2b.y) : 0.f;
        float w6 = a1.z ? ((x2b.z >= t1) ? p1 * p2b.z : q1 * q2b.z) : 0.f;
        float w7 = a1.w ? ((x2b.w >= t1) ? p1 * p2b.w : q1 * q2b.w) : 0.f;
        dn += ((w0 + w1) + (w2 + w3)) + ((w4 + w5) + (w6 + w7));
        union { short8 s; uint4 u; } r;
        r.u.x = pack_bf2(w0, w1); r.u.y = pack_bf2(w2, w3);
        r.u.z = pack_bf2(w4, w5); r.u.w = pack_bf2(w6, w7);
        return r.s;
    };

    auto body = [&](int it, int4* cur, int4* nxt) {
        if (it + 1 < NIT) load_adj(it + 1, nxt);   // HBM prefetch, consumed next body
#pragma unroll
        for (int kh = 0; kh < 2; kh++) {
            int jl = it * BK + kh * 32 + q * 8;
            float4 x2a = *reinterpret_cast<const float4*>(&sW2[jl]);
            float4 x2b = *reinterpret_cast<const float4*>(&sW2[jl + 4]);
            float4 p2a = *reinterpret_cast<const float4*>(&sP2[jl]);
            float4 p2b = *reinterpret_cast<const float4*>(&sP2[jl + 4]);
            float4 q2a = *reinterpret_cast<const float4*>(&sQ2[jl]);
            float4 q2b = *reinterpret_cast<const float4*>(&sQ2[jl + 4]);
            short8 af = gen_af(cur[kh * 2 + 0], cur[kh * 2 + 1], x2a, x2b,
                               p2a, p2b, q2a, q2b, den);
            const unsigned short* vk = vbl + it * BK + kh * 32;
#pragma unroll
            for (int nt = 0; nt < 8; nt++) {
                short8 bf = *reinterpret_cast<const short8*>(vk + (size_t)nt * 16 * N);
                acc[nt] = __builtin_amdgcn_mfma_f32_16x16x32_bf16(af, bf, acc[nt], 0, 0, 0);
            }
        }
    };

    load_adj(0, aregA);
#pragma unroll 1
    for (int ith = 0; ith < NIT / 2; ith++) {
        body(ith * 2 + 0, aregA, aregB);
        body(ith * 2 + 1, aregB, aregA);
    }

    // epilogue: denominator (reduce over q) + partial numerator, plain stores
    den += __shfl_xor(den, 16);
    den += __shfl_xor(den, 32);
    float* dp = den_part + (size_t)split * BN;
    if (q == 0) dp[gi] = den;
    float* hp = h_part + (size_t)split * BN * F;
    int orow = b * N + i0 + widx * 16 + q * 4;  // C/D: row = q*4+reg, col = m
#pragma unroll
    for (int nt = 0; nt < 8; nt++)
#pragma unroll
        for (int r = 0; r < 4; r++)
            hp[(size_t)(orow + r) * F + nt * 16 + m] = acc[nt][r];
}

// ---------------- K4: out = leaky( ((sum_s h_s)/(sum_s den_s)) @ Wo^T ) ----------------
__global__ __launch_bounds__(256) void k_out(const float* __restrict__ h_part,
                                             const float* __restrict__ den_part,
                                             const float* __restrict__ Wo_w,
                                             float* __restrict__ out) {
    __shared__ float hs[32][F];    // 16 KB
    __shared__ float Ws[F][129];   // 66 KB
    int t = threadIdx.x;
    int row0 = blockIdx.x * 32;    // flat row in [0, BN)
    {
        const float4* src = reinterpret_cast<const float4*>(Wo_w);
#pragma unroll
        for (int u = 0; u < 16; u++) {
            int unit = u * 256 + t;
            int r = unit >> 5, s = unit & 31;
            float4 val = src[unit];
            Ws[r][s * 4 + 0] = val.x; Ws[r][s * 4 + 1] = val.y;
            Ws[r][s * 4 + 2] = val.z; Ws[r][s * 4 + 3] = val.w;
        }
    }
#pragma unroll
    for (int u = 0; u < 4; u++) {
        int unit = u * 256 + t;
        int r = unit >> 5, s = unit & 31;
        size_t off = (size_t)(row0 + r) * F + s * 4;
        float4 h0 = *reinterpret_cast<const float4*>(h_part + off);
        float4 h1 = *reinterpret_cast<const float4*>(h_part + (size_t)BN * F + off);
        float4 h2 = *reinterpret_cast<const float4*>(h_part + (size_t)2 * BN * F + off);
        float4 h3 = *reinterpret_cast<const float4*>(h_part + (size_t)3 * BN * F + off);
        float dsum = den_part[row0 + r] + den_part[BN + row0 + r] +
                     den_part[2 * BN + row0 + r] + den_part[3 * BN + row0 + r];
        float inv = 1.f / dsum;
        hs[r][s * 4 + 0] = (h0.x + h1.x + h2.x + h3.x) * inv;
        hs[r][s * 4 + 1] = (h0.y + h1.y + h2.y + h3.y) * inv;
        hs[r][s * 4 + 2] = (h0.z + h1.z + h2.z + h3.z) * inv;
        hs[r][s * 4 + 3] = (h0.w + h1.w + h2.w + h3.w) * inv;
    }
    __syncthreads();
    int f = t & 127, g = t >> 7;
    float acc[16];
#pragma unroll
    for (int r = 0; r < 16; r++) acc[r] = 0.f;
    for (int kk = 0; kk < F; kk++) {
        float wk = Ws[f][kk];
#pragma unroll
        for (int r = 0; r < 16; r++) acc[r] = fmaf(hs[g * 16 + r][kk], wk, acc[r]);
    }
#pragma unroll
    for (int r = 0; r < 16; r++) out[(size_t)(row0 + g * 16 + r) * F + f] = leaky(acc[r]);
}

extern "C" void kernel_launch(void* const* d_in, const int* in_sizes, int n_in,
                              void* d_out, int out_size, void* d_ws, size_t ws_size,
                              hipStream_t stream) {
    const float* q    = (const float*)d_in[0];
    const float* k    = (const float*)d_in[1];
    const float* v    = (const float*)d_in[2];
    const int*   adj  = (const int*)d_in[3];
    const float* Wq_w = (const float*)d_in[4];
    const float* Wq_b = (const float*)d_in[5];
    const float* Wk_w = (const float*)d_in[6];
    const float* Wk_b = (const float*)d_in[7];
    const float* Wv_w = (const float*)d_in[8];
    const float* Wv_b = (const float*)d_in[9];
    const float* a    = (const float*)d_in[10];
    const float* Wo_w = (const float*)d_in[11];
    float* out = (float*)d_out;
    float* ws = (float*)d_ws;

    unsigned short* vpT = (unsigned short*)ws;        // BN*F bf16 = BN*F/2 floats
    float* h_part   = ws + BN * F / 2;                // SPLITS*BN*F
    float* den_part = h_part + (size_t)SPLITS * BN * F;  // SPLITS*BN
    float* Wh1 = den_part + SPLITS * BN;
    float* Wh2 = Wh1 + BN;
    float* P1  = Wh2 + BN;
    float* Q1  = P1 + BN;
    float* P2  = Q1 + BN;
    float* Q2  = P2 + BN;
    float* c1  = Q2 + BN;                             // F
    float* c2  = c1 + F;                              // F
    float* d12 = c2 + F;                              // 2
    float* M2  = d12 + 2;                             // B

    k_prep<<<1, 256, 0, stream>>>(Wq_w, Wq_b, Wk_w, Wk_b, a, c1, c2, d12);
    k_wh<<<BN / 8, 256, 0, stream>>>(q, k, c1, c2, d12, Wh1, Wh2);
    k_max2<<<B, 256, 0, stream>>>(Wh2, M2);
    k_tab<<<BN / 256, 256, 0, stream>>>(Wh1, Wh2, M2, P1, Q1, P2, Q2);
    k_vp<<<BN / 32, 256, 0, stream>>>(v, Wv_w, Wv_b, vpT);
    k_attn<<<B * 64 * SPLITS, 256, 0, stream>>>(vpT, adj, Wh1, P1, Q1, P2, Q2, Wh2,
                                                h_part, den_part);
    k_out<<<BN / 32, 256, 0, stream>>>(h_part, den_part, Wo_w, out);
}

// Round 5
// 538.693 us; speedup vs baseline: 1.1743x; 1.1743x over previous
//
#include <hip/hip_runtime.h>

// GraphAttentionLayer: B=4, N=4096, F=128, fp32 in/out.
//   w_ij = adj_ij * ( Wh2_j >= -Wh1_i ? P1_i*P2_j : Q1_i*Q2_j )   (softmax scale-invariance
//   + separability of exp(leaky(x+y)) per branch), h = (w @ vp) / rowsum(w), out = leaky(h@Wo^T).
// v5: adj bit-packed by a streaming ballot pre-pass (268 MB -> 8.4 MB), so k_attn's inner
// loop reads 1 bit/edge. k_attn returns to the LDS-staged MFMA structure (v3 dbuf, one
// barrier/iter) with 3 blocks/CU. A-frag (w) generated in-register from bit tests.

constexpr int B = 4, N = 4096, F = 128;
constexpr int BN = B * N;
constexpr int BK = 64;
constexpr int SPLITS = 4;
constexpr int JC = N / SPLITS;   // 1024 j per block
constexpr int NIT = JC / BK;     // 16 iterations
#define ALPHA 0.1f

using float4v = __attribute__((ext_vector_type(4))) float;
using short8 = __attribute__((ext_vector_type(8))) short;
typedef unsigned long long ull;

__device__ __forceinline__ float leaky(float x) { return x >= 0.f ? x : ALPHA * x; }
__device__ __forceinline__ unsigned short f2bf(float x) {  // RNE float->bf16
    unsigned u = __float_as_uint(x);
    u = (u + 0x7FFFu + ((u >> 16) & 1u)) >> 16;
    return (unsigned short)u;
}
// pack two floats -> two RNE bf16 in one dword: {bf(hi)[31:16], bf(lo)[15:0]}
__device__ __forceinline__ unsigned pack_bf2(float lo, float hi) {
    unsigned a = __float_as_uint(lo), b2 = __float_as_uint(hi);
    a = a + 0x7FFFu + ((a >> 16) & 1u);
    b2 = b2 + 0x7FFFu + ((b2 >> 16) & 1u);
    return __builtin_amdgcn_perm(b2, a, 0x07060302u);  // bytes: b2[3],b2[2],a[3],a[2]
}

// ---------------- K-1: adj bit-pack (streaming, coalesced, ballot) ----------------
__global__ __launch_bounds__(256) void k_pack(const int* __restrict__ adj,
                                              ull* __restrict__ pack) {
    const long long GROUPS = (long long)B * N * N / 256;  // 262144 groups of 256 ints
    int t = threadIdx.x;
    int lane = t & 63;
    long long gw = ((long long)blockIdx.x * 256 + t) >> 6;  // global wave id
    long long nw = ((long long)gridDim.x * 256) >> 6;
    for (long long g = gw; g < GROUPS; g += nw) {
        long long base = g * 256;
        ull m0 = __ballot(adj[base + lane] != 0);
        ull m1 = __ballot(adj[base + 64 + lane] != 0);
        ull m2 = __ballot(adj[base + 128 + lane] != 0);
        ull m3 = __ballot(adj[base + 192 + lane] != 0);
        if (lane < 4) {
            ull w = (lane == 0) ? m0 : (lane == 1) ? m1 : (lane == 2) ? m2 : m3;
            pack[g * 4 + lane] = w;
        }
    }
}

// ---------------- K0: c1, c2, d1, d2 ----------------
__global__ void k_prep(const float* __restrict__ Wq_w, const float* __restrict__ Wq_b,
                       const float* __restrict__ Wk_w, const float* __restrict__ Wk_b,
                       const float* __restrict__ a, float* __restrict__ c1,
                       float* __restrict__ c2, float* __restrict__ d12) {
    __shared__ float as[2 * F];
    __shared__ float red[2 * F];
    int t = threadIdx.x;  // 256
    as[t] = a[t];
    __syncthreads();
    int f = t & 127;
    const float* W = (t < F) ? Wq_w : Wk_w;
    const float* ao = (t < F) ? as : as + F;
    float s = 0.f;
#pragma unroll 8
    for (int o = 0; o < F; o++) s = fmaf(W[o * F + f], ao[o], s);
    if (t < F) c1[f] = s; else c2[f] = s;
    red[t] = (t < F) ? Wq_b[f] * as[f] : Wk_b[f] * as[F + f];
    __syncthreads();
    for (int st = 64; st > 0; st >>= 1) {
        if (f < st) red[t] += red[t + st];
        __syncthreads();
    }
    if (t == 0) d12[0] = red[0];
    if (t == F) d12[1] = red[F];
}

// ---------------- K1: Wh1, Wh2 ----------------
__global__ void k_wh(const float* __restrict__ q, const float* __restrict__ k,
                     const float* __restrict__ c1, const float* __restrict__ c2,
                     const float* __restrict__ d12,
                     float* __restrict__ Wh1, float* __restrict__ Wh2) {
    __shared__ float c1s[F], c2s[F];
    int t = threadIdx.x;
    if (t < F) c1s[t] = c1[t]; else c2s[t - F] = c2[t - F];
    __syncthreads();
    int row = blockIdx.x * 8 + (t >> 5);
    int lane = t & 31;
    float4 q4 = reinterpret_cast<const float4*>(q)[row * 32 + lane];
    float4 k4 = reinterpret_cast<const float4*>(k)[row * 32 + lane];
    float s1 = q4.x * c1s[lane * 4 + 0] + q4.y * c1s[lane * 4 + 1] +
               q4.z * c1s[lane * 4 + 2] + q4.w * c1s[lane * 4 + 3];
    float s2 = k4.x * c2s[lane * 4 + 0] + k4.y * c2s[lane * 4 + 1] +
               k4.z * c2s[lane * 4 + 2] + k4.w * c2s[lane * 4 + 3];
    for (int m = 16; m > 0; m >>= 1) { s1 += __shfl_xor(s1, m); s2 += __shfl_xor(s2, m); }
    if (lane == 0) { Wh1[row] = s1 + d12[0]; Wh2[row] = s2 + d12[1]; }
}

// ---------------- K1b: per-batch max of Wh2 ----------------
__global__ void k_max2(const float* __restrict__ Wh2, float* __restrict__ M2) {
    int b = blockIdx.x, t = threadIdx.x;
    float m = -1e30f;
    for (int i = t; i < N; i += 256) m = fmaxf(m, Wh2[b * N + i]);
    __shared__ float red[256];
    red[t] = m;
    __syncthreads();
    for (int s = 128; s > 0; s >>= 1) { if (t < s) red[t] = fmaxf(red[t], red[t + s]); __syncthreads(); }
    if (t == 0) M2[b] = red[0];
}

// ---------------- K1c: exp tables ----------------
__global__ void k_tab(const float* __restrict__ Wh1, const float* __restrict__ Wh2,
                      const float* __restrict__ M2,
                      float* __restrict__ P1, float* __restrict__ Q1,
                      float* __restrict__ P2, float* __restrict__ Q2) {
    int i = blockIdx.x * 256 + threadIdx.x;
    int b = i >> 12;  // N = 4096
    float w1 = Wh1[i], w2 = Wh2[i];
    float mi = leaky(w1 + M2[b]);  // per-row shift (cancels in h; range only)
    P1[i] = __expf(w1 - mi);
    Q1[i] = __expf(ALPHA * w1 - mi);
    P2[i] = __expf(w2);
    Q2[i] = __expf(ALPHA * w2);
}

// ---------------- K2: vpT = bf16( (v @ Wv^T + bv)^T ), layout [B][F][N] ----------------
__global__ __launch_bounds__(256) void k_vp(const float* __restrict__ v,
                                            const float* __restrict__ Wv_w,
                                            const float* __restrict__ Wv_b,
                                            unsigned short* __restrict__ vpT) {
    __shared__ float vs[32][F];            // 16 KB
    __shared__ float Ws[F][129];           // 66 KB, pad -> conflict-free column reads
    __shared__ unsigned short ts[F][40];   // 10 KB transpose tile (pad 8)
    int t = threadIdx.x;
    int row0g = blockIdx.x * 32;           // flat row in [0, BN)
    int b = row0g >> 12;
    int row0 = row0g & (N - 1);
    {
        const float4* src = reinterpret_cast<const float4*>(v + row0g * F);
        float4* dst = reinterpret_cast<float4*>(&vs[0][0]);
#pragma unroll
        for (int u = 0; u < 4; u++) dst[u * 256 + t] = src[u * 256 + t];
    }
    {
        const float4* src = reinterpret_cast<const float4*>(Wv_w);
#pragma unroll
        for (int u = 0; u < 16; u++) {
            int unit = u * 256 + t;
            int r = unit >> 5, s = unit & 31;
            float4 val = src[unit];
            Ws[r][s * 4 + 0] = val.x; Ws[r][s * 4 + 1] = val.y;
            Ws[r][s * 4 + 2] = val.z; Ws[r][s * 4 + 3] = val.w;
        }
    }
    int f = t & 127, g = t >> 7;
    float bias = Wv_b[f];
    __syncthreads();
    float acc[16];
#pragma unroll
    for (int r = 0; r < 16; r++) acc[r] = bias;
    for (int kk = 0; kk < F; kk++) {
        float wk = Ws[f][kk];
#pragma unroll
        for (int r = 0; r < 16; r++) acc[r] = fmaf(vs[g * 16 + r][kk], wk, acc[r]);
    }
#pragma unroll
    for (int r = 0; r < 16; r++) ts[f][g * 16 + r] = f2bf(acc[r]);
    __syncthreads();
    int fr = t >> 1, hseg = t & 1;
    uint4 d0 = *reinterpret_cast<uint4*>(&ts[fr][hseg * 16]);
    uint4 d1 = *reinterpret_cast<uint4*>(&ts[fr][hseg * 16 + 8]);
    unsigned short* dst = vpT + ((size_t)(b * F + fr) * N + row0 + hseg * 16);
    *reinterpret_cast<uint4*>(dst) = d0;
    *reinterpret_cast<uint4*>(dst + 8) = d1;
}

// ---------------- K3: MFMA attention, LDS-staged vpT, bit-packed adj ----------------
__global__ __launch_bounds__(256, 3) void k_attn(
    const unsigned short* __restrict__ vpT, const ull* __restrict__ pack,
    const float* __restrict__ Wh1, const float* __restrict__ P1, const float* __restrict__ Q1,
    const float* __restrict__ P2, const float* __restrict__ Q2, const float* __restrict__ Wh2,
    float* __restrict__ h_part, float* __restrict__ den_part) {
    __shared__ __align__(16) unsigned short bs[2][F][72];      // 36.9 KB dbuf, pad 72
    __shared__ __align__(16) float sP2[JC], sQ2[JC], sW2[JC];  // 12 KB
    int t = threadIdx.x;
    int idx = blockIdx.x;            // 1024 = B * 64 tiles * 4 splits
    int split = idx & 3;
    int tile = (idx >> 2) & 63;
    int b = idx >> 8;
    int i0 = tile * 64;
    int jb0 = split * JC;
    int widx = t >> 6, lane = t & 63, m = lane & 15, q = lane >> 4;

    {  // preload P2/Q2/W2 tables for the whole j-slice
        reinterpret_cast<float4*>(sP2)[t] = reinterpret_cast<const float4*>(P2 + b * N + jb0)[t];
        reinterpret_cast<float4*>(sQ2)[t] = reinterpret_cast<const float4*>(Q2 + b * N + jb0)[t];
        reinterpret_cast<float4*>(sW2)[t] = reinterpret_cast<const float4*>(Wh2 + b * N + jb0)[t];
    }

    int gi = b * N + i0 + widx * 16 + m;   // this lane's A-row
    float p1 = P1[gi], q1 = Q1[gi], t1 = -Wh1[gi];
    const ull* pk = pack + (size_t)gi * (N / 64) + jb0 / 64;  // one 64-bit word per iter
    const unsigned short* vb = vpT + (size_t)b * F * N + jb0;

    uint4 sreg[4];
    auto load_stage = [&](int it) {
#pragma unroll
        for (int u = 0; u < 4; u++) {
            int unit = u * 256 + t;
            int r = unit >> 3, s = unit & 7;
            sreg[u] = *reinterpret_cast<const uint4*>(vb + (size_t)r * N + it * BK + s * 8);
        }
    };
    auto write_stage = [&](int pb) {
#pragma unroll
        for (int u = 0; u < 4; u++) {
            int unit = u * 256 + t;
            int r = unit >> 3, s = unit & 7;
            *reinterpret_cast<uint4*>(&bs[pb][r][s * 8]) = sreg[u];
        }
    };

    float4v acc[8];
#pragma unroll
    for (int nt = 0; nt < 8; nt++) acc[nt] = (float4v){0.f, 0.f, 0.f, 0.f};
    float den = 0.f;

    // w-gen from 8 adjacency bits -> bf16 A-frag
    auto gen_af = [&](unsigned bt, const float4& x2a, const float4& x2b,
                      const float4& p2a, const float4& p2b, const float4& q2a,
                      const float4& q2b, float& dn) -> short8 {
        float w0 = (bt & 1u)   ? ((x2a.x >= t1) ? p1 * p2a.x : q1 * q2a.x) : 0.f;
        float w1 = (bt & 2u)   ? ((x2a.y >= t1) ? p1 * p2a.y : q1 * q2a.y) : 0.f;
        float w2 = (bt & 4u)   ? ((x2a.z >= t1) ? p1 * p2a.z : q1 * q2a.z) : 0.f;
        float w3 = (bt & 8u)   ? ((x2a.w >= t1) ? p1 * p2a.w : q1 * q2a.w) : 0.f;
        float w4 = (bt & 16u)  ? ((x2b.x >= t1) ? p1 * p2b.x : q1 * q2b.x) : 0.f;
        float w5 = (bt & 32u)  ? ((x2b.y >= t1) ? p1 * p2b.y : q1 * q2b.y) : 0.f;
        float w6 = (bt & 64u)  ? ((x2b.z >= t1) ? p1 * p2b.z : q1 * q2b.z) : 0.f;
        float w7 = (bt & 128u) ? ((x2b.w >= t1) ? p1 * p2b.w : q1 * q2b.w) : 0.f;
        dn += ((w0 + w1) + (w2 + w3)) + ((w4 + w5) + (w6 + w7));
        union { short8 s; uint4 u; } r;
        r.u.x = pack_bf2(w0, w1); r.u.y = pack_bf2(w2, w3);
        r.u.z = pack_bf2(w4, w5); r.u.w = pack_bf2(w6, w7);
        return r.s;
    };

    auto body = [&](int it, int pb, ull pw, ull& pwn) {
        if (it + 1 < NIT) {  // prefetch next tile (global->reg) under this tile's compute
            load_stage(it + 1);
            pwn = pk[it + 1];
        }
#pragma unroll
        for (int kh = 0; kh < 2; kh++) {
            int jl = it * BK + kh * 32 + q * 8;
            float4 x2a = *reinterpret_cast<const float4*>(&sW2[jl]);
            float4 x2b = *reinterpret_cast<const float4*>(&sW2[jl + 4]);
            float4 p2a = *reinterpret_cast<const float4*>(&sP2[jl]);
            float4 p2b = *reinterpret_cast<const float4*>(&sP2[jl + 4]);
            float4 q2a = *reinterpret_cast<const float4*>(&sQ2[jl]);
            float4 q2b = *reinterpret_cast<const float4*>(&sQ2[jl + 4]);
            unsigned bt = ((unsigned)(pw >> (kh * 32)) >> (q * 8)) & 0xFFu;
            short8 af = gen_af(bt, x2a, x2b, p2a, p2b, q2a, q2b, den);
#pragma unroll
            for (int nt = 0; nt < 8; nt++) {
                short8 bf = *reinterpret_cast<const short8*>(&bs[pb][nt * 16 + m][kh * 32 + q * 8]);
                acc[nt] = __builtin_amdgcn_mfma_f32_16x16x32_bf16(af, bf, acc[nt], 0, 0, 0);
            }
        }
        if (it + 1 < NIT) write_stage(pb ^ 1);
        __syncthreads();
    };

    // prologue
    ull pwA, pwB;
    load_stage(0);
    pwA = pk[0];
    write_stage(0);
    __syncthreads();   // covers table writes too

#pragma unroll 1
    for (int ith = 0; ith < NIT / 2; ith++) {
        body(ith * 2 + 0, 0, pwA, pwB);
        body(ith * 2 + 1, 1, pwB, pwA);
    }

    // epilogue: denominator (reduce over q) + partial numerator, plain stores
    den += __shfl_xor(den, 16);
    den += __shfl_xor(den, 32);
    float* dp = den_part + (size_t)split * BN;
    if (q == 0) dp[gi] = den;
    float* hp = h_part + (size_t)split * BN * F;
    int orow = b * N + i0 + widx * 16 + q * 4;  // C/D: row = q*4+reg, col = m
#pragma unroll
    for (int nt = 0; nt < 8; nt++)
#pragma unroll
        for (int r = 0; r < 4; r++)
            hp[(size_t)(orow + r) * F + nt * 16 + m] = acc[nt][r];
}

// ---------------- K4: out = leaky( ((sum_s h_s)/(sum_s den_s)) @ Wo^T ) ----------------
__global__ __launch_bounds__(256) void k_out(const float* __restrict__ h_part,
                                             const float* __restrict__ den_part,
                                             const float* __restrict__ Wo_w,
                                             float* __restrict__ out) {
    __shared__ float hs[32][F];    // 16 KB
    __shared__ float Ws[F][129];   // 66 KB
    int t = threadIdx.x;
    int row0 = blockIdx.x * 32;    // flat row in [0, BN)
    {
        const float4* src = reinterpret_cast<const float4*>(Wo_w);
#pragma unroll
        for (int u = 0; u < 16; u++) {
            int unit = u * 256 + t;
            int r = unit >> 5, s = unit & 31;
            float4 val = src[unit];
            Ws[r][s * 4 + 0] = val.x; Ws[r][s * 4 + 1] = val.y;
            Ws[r][s * 4 + 2] = val.z; Ws[r][s * 4 + 3] = val.w;
        }
    }
#pragma unroll
    for (int u = 0; u < 4; u++) {
        int unit = u * 256 + t;
        int r = unit >> 5, s = unit & 31;
        size_t off = (size_t)(row0 + r) * F + s * 4;
        float4 h0 = *reinterpret_cast<const float4*>(h_part + off);
        float4 h1 = *reinterpret_cast<const float4*>(h_part + (size_t)BN * F + off);
        float4 h2 = *reinterpret_cast<const float4*>(h_part + (size_t)2 * BN * F + off);
        float4 h3 = *reinterpret_cast<const float4*>(h_part + (size_t)3 * BN * F + off);
        float dsum = den_part[row0 + r] + den_part[BN + row0 + r] +
                     den_part[2 * BN + row0 + r] + den_part[3 * BN + row0 + r];
        float inv = 1.f / dsum;
        hs[r][s * 4 + 0] = (h0.x + h1.x + h2.x + h3.x) * inv;
        hs[r][s * 4 + 1] = (h0.y + h1.y + h2.y + h3.y) * inv;
        hs[r][s * 4 + 2] = (h0.z + h1.z + h2.z + h3.z) * inv;
        hs[r][s * 4 + 3] = (h0.w + h1.w + h2.w + h3.w) * inv;
    }
    __syncthreads();
    int f = t & 127, g = t >> 7;
    float acc[16];
#pragma unroll
    for (int r = 0; r < 16; r++) acc[r] = 0.f;
    for (int kk = 0; kk < F; kk++) {
        float wk = Ws[f][kk];
#pragma unroll
        for (int r = 0; r < 16; r++) acc[r] = fmaf(hs[g * 16 + r][kk], wk, acc[r]);
    }
#pragma unroll
    for (int r = 0; r < 16; r++) out[(size_t)(row0 + g * 16 + r) * F + f] = leaky(acc[r]);
}

extern "C" void kernel_launch(void* const* d_in, const int* in_sizes, int n_in,
                              void* d_out, int out_size, void* d_ws, size_t ws_size,
                              hipStream_t stream) {
    const float* q    = (const float*)d_in[0];
    const float* k    = (const float*)d_in[1];
    const float* v    = (const float*)d_in[2];
    const int*   adj  = (const int*)d_in[3];
    const float* Wq_w = (const float*)d_in[4];
    const float* Wq_b = (const float*)d_in[5];
    const float* Wk_w = (const float*)d_in[6];
    const float* Wk_b = (const float*)d_in[7];
    const float* Wv_w = (const float*)d_in[8];
    const float* Wv_b = (const float*)d_in[9];
    const float* a    = (const float*)d_in[10];
    const float* Wo_w = (const float*)d_in[11];
    float* out = (float*)d_out;
    float* ws = (float*)d_ws;

    unsigned short* vpT = (unsigned short*)ws;        // BN*F bf16 = BN*F/2 floats
    float* h_part   = ws + BN * F / 2;                // SPLITS*BN*F
    float* den_part = h_part + (size_t)SPLITS * BN * F;  // SPLITS*BN
    float* Wh1 = den_part + SPLITS * BN;
    float* Wh2 = Wh1 + BN;
    float* P1  = Wh2 + BN;
    float* Q1  = P1 + BN;
    float* P2  = Q1 + BN;
    float* Q2  = P2 + BN;
    float* c1  = Q2 + BN;                             // F
    float* c2  = c1 + F;                              // F
    float* d12 = c2 + F;                              // 2
    float* M2  = d12 + 2;                             // B
    size_t off = (size_t)((M2 + B) - ws);
    off = (off + 1) & ~(size_t)1;                     // 8-byte align
    ull* pack = (ull*)(ws + off);                     // BN * (N/64) uint64 = 8 MB

    k_pack<<<2048, 256, 0, stream>>>(adj, pack);
    k_prep<<<1, 256, 0, stream>>>(Wq_w, Wq_b, Wk_w, Wk_b, a, c1, c2, d12);
    k_wh<<<BN / 8, 256, 0, stream>>>(q, k, c1, c2, d12, Wh1, Wh2);
    k_max2<<<B, 256, 0, stream>>>(Wh2, M2);
    k_tab<<<BN / 256, 256, 0, stream>>>(Wh1, Wh2, M2, P1, Q1, P2, Q2);
    k_vp<<<BN / 32, 256, 0, stream>>>(v, Wv_w, Wv_b, vpT);
    k_attn<<<B * 64 * SPLITS, 256, 0, stream>>>(vpT, pack, Wh1, P1, Q1, P2, Q2, Wh2,
                                                h_part, den_part);
    k_out<<<BN / 32, 256, 0, stream>>>(h_part, den_part, Wo_w, out);
}

// Round 6
// 522.954 us; speedup vs baseline: 1.2097x; 1.0301x over previous
//
#include <hip/hip_runtime.h>

// GraphAttentionLayer: B=4, N=4096, F=128, fp32 in/out.
//   w_ij = adj_ij * ( Wh2_j >= -Wh1_i ? P1_i*P2_j : Q1_i*Q2_j )   (softmax scale-invariance
//   + separability of exp(leaky(x+y)) per branch), h = (w @ vp) / rowsum(w), out = leaky(h@Wo^T).
// v6: adj -> bits (k_pack) -> TRANSPOSED bits packT[b][jw][i] (k_ptrans) so k_attn's per-iter
// bit load is one coalesced line per wave. k_attn: Mblock=128, Mw=32 (2 row-tiles/wave share
// B-frags), LDS dbuf staging, 4-way j-split, plain partial stores. k_out combines+GEMM+leaky.

constexpr int B = 4, N = 4096, F = 128;
constexpr int BN = B * N;
constexpr int BK = 64;
constexpr int SPLITS = 4;
constexpr int JC = N / SPLITS;   // 1024 j per block
constexpr int NIT = JC / BK;     // 16 iterations
#define ALPHA 0.1f

using float4v = __attribute__((ext_vector_type(4))) float;
using short8 = __attribute__((ext_vector_type(8))) short;
typedef unsigned long long ull;

__device__ __forceinline__ float leaky(float x) { return x >= 0.f ? x : ALPHA * x; }
__device__ __forceinline__ unsigned short f2bf(float x) {  // RNE float->bf16
    unsigned u = __float_as_uint(x);
    u = (u + 0x7FFFu + ((u >> 16) & 1u)) >> 16;
    return (unsigned short)u;
}
// pack two floats -> two RNE bf16 in one dword: {bf(hi)[31:16], bf(lo)[15:0]}
__device__ __forceinline__ unsigned pack_bf2(float lo, float hi) {
    unsigned a = __float_as_uint(lo), b2 = __float_as_uint(hi);
    a = a + 0x7FFFu + ((a >> 16) & 1u);
    b2 = b2 + 0x7FFFu + ((b2 >> 16) & 1u);
    return __builtin_amdgcn_perm(b2, a, 0x07060302u);  // bytes: b2[3],b2[2],a[3],a[2]
}

// ---------------- K-1a: adj bit-pack (streaming, coalesced, ballot) ----------------
__global__ __launch_bounds__(256) void k_pack(const int* __restrict__ adj,
                                              ull* __restrict__ pack) {
    const long long GROUPS = (long long)B * N * N / 256;  // groups of 256 ints
    int t = threadIdx.x;
    int lane = t & 63;
    long long gw = ((long long)blockIdx.x * 256 + t) >> 6;  // global wave id
    long long nw = ((long long)gridDim.x * 256) >> 6;
    for (long long g = gw; g < GROUPS; g += nw) {
        long long base = g * 256;
        ull m0 = __ballot(adj[base + lane] != 0);
        ull m1 = __ballot(adj[base + 64 + lane] != 0);
        ull m2 = __ballot(adj[base + 128 + lane] != 0);
        ull m3 = __ballot(adj[base + 192 + lane] != 0);
        if (lane < 4) {
            ull w = (lane == 0) ? m0 : (lane == 1) ? m1 : (lane == 2) ? m2 : m3;
            pack[g * 4 + lane] = w;
        }
    }
}

// ---------------- K-1b: transpose bits: pack[b*N+i][jw] -> packT[(b*64+jw)][i] ----------------
__global__ __launch_bounds__(256) void k_ptrans(const ull* __restrict__ pack,
                                                ull* __restrict__ packT) {
    __shared__ ull tile[64][65];
    int t = threadIdx.x;
    int blk = blockIdx.x;          // 256 = B * 64 i-tiles
    int b = blk >> 6;
    int i0 = (blk & 63) * 64;
#pragma unroll
    for (int u = 0; u < 16; u++) {
        int unit = u * 256 + t;    // r = unit>>6 (row), jw = unit&63
        tile[unit >> 6][unit & 63] =
            pack[((size_t)b * N + i0 + (unit >> 6)) * 64 + (unit & 63)];
    }
    __syncthreads();
#pragma unroll
    for (int u = 0; u < 16; u++) {
        int unit = u * 256 + t;    // jw = unit>>6, il = unit&63
        packT[((size_t)b * 64 + (unit >> 6)) * N + i0 + (unit & 63)] =
            tile[unit & 63][unit >> 6];
    }
}

// ---------------- K0: c1, c2, d1, d2 ----------------
__global__ void k_prep(const float* __restrict__ Wq_w, const float* __restrict__ Wq_b,
                       const float* __restrict__ Wk_w, const float* __restrict__ Wk_b,
                       const float* __restrict__ a, float* __restrict__ c1,
                       float* __restrict__ c2, float* __restrict__ d12) {
    __shared__ float as[2 * F];
    __shared__ float red[2 * F];
    int t = threadIdx.x;  // 256
    as[t] = a[t];
    __syncthreads();
    int f = t & 127;
    const float* W = (t < F) ? Wq_w : Wk_w;
    const float* ao = (t < F) ? as : as + F;
    float s = 0.f;
#pragma unroll 8
    for (int o = 0; o < F; o++) s = fmaf(W[o * F + f], ao[o], s);
    if (t < F) c1[f] = s; else c2[f] = s;
    red[t] = (t < F) ? Wq_b[f] * as[f] : Wk_b[f] * as[F + f];
    __syncthreads();
    for (int st = 64; st > 0; st >>= 1) {
        if (f < st) red[t] += red[t + st];
        __syncthreads();
    }
    if (t == 0) d12[0] = red[0];
    if (t == F) d12[1] = red[F];
}

// ---------------- K1: Wh1, Wh2 ----------------
__global__ void k_wh(const float* __restrict__ q, const float* __restrict__ k,
                     const float* __restrict__ c1, const float* __restrict__ c2,
                     const float* __restrict__ d12,
                     float* __restrict__ Wh1, float* __restrict__ Wh2) {
    __shared__ float c1s[F], c2s[F];
    int t = threadIdx.x;
    if (t < F) c1s[t] = c1[t]; else c2s[t - F] = c2[t - F];
    __syncthreads();
    int row = blockIdx.x * 8 + (t >> 5);
    int lane = t & 31;
    float4 q4 = reinterpret_cast<const float4*>(q)[row * 32 + lane];
    float4 k4 = reinterpret_cast<const float4*>(k)[row * 32 + lane];
    float s1 = q4.x * c1s[lane * 4 + 0] + q4.y * c1s[lane * 4 + 1] +
               q4.z * c1s[lane * 4 + 2] + q4.w * c1s[lane * 4 + 3];
    float s2 = k4.x * c2s[lane * 4 + 0] + k4.y * c2s[lane * 4 + 1] +
               k4.z * c2s[lane * 4 + 2] + k4.w * c2s[lane * 4 + 3];
    for (int m = 16; m > 0; m >>= 1) { s1 += __shfl_xor(s1, m); s2 += __shfl_xor(s2, m); }
    if (lane == 0) { Wh1[row] = s1 + d12[0]; Wh2[row] = s2 + d12[1]; }
}

// ---------------- K1b: per-batch max of Wh2 ----------------
__global__ void k_max2(const float* __restrict__ Wh2, float* __restrict__ M2) {
    int b = blockIdx.x, t = threadIdx.x;
    float m = -1e30f;
    for (int i = t; i < N; i += 256) m = fmaxf(m, Wh2[b * N + i]);
    __shared__ float red[256];
    red[t] = m;
    __syncthreads();
    for (int s = 128; s > 0; s >>= 1) { if (t < s) red[t] = fmaxf(red[t], red[t + s]); __syncthreads(); }
    if (t == 0) M2[b] = red[0];
}

// ---------------- K1c: exp tables ----------------
__global__ void k_tab(const float* __restrict__ Wh1, const float* __restrict__ Wh2,
                      const float* __restrict__ M2,
                      float* __restrict__ P1, float* __restrict__ Q1,
                      float* __restrict__ P2, float* __restrict__ Q2) {
    int i = blockIdx.x * 256 + threadIdx.x;
    int b = i >> 12;  // N = 4096
    float w1 = Wh1[i], w2 = Wh2[i];
    float mi = leaky(w1 + M2[b]);  // per-row shift (cancels in h; range only)
    P1[i] = __expf(w1 - mi);
    Q1[i] = __expf(ALPHA * w1 - mi);
    P2[i] = __expf(w2);
    Q2[i] = __expf(ALPHA * w2);
}

// ---------------- K2: vpT = bf16( (v @ Wv^T + bv)^T ), layout [B][F][N] ----------------
__global__ __launch_bounds__(256) void k_vp(const float* __restrict__ v,
                                            const float* __restrict__ Wv_w,
                                            const float* __restrict__ Wv_b,
                                            unsigned short* __restrict__ vpT) {
    __shared__ float vs[32][F];            // 16 KB
    __shared__ float Ws[F][129];           // 66 KB, pad -> conflict-free column reads
    __shared__ unsigned short ts[F][40];   // 10 KB transpose tile (pad 8)
    int t = threadIdx.x;
    int row0g = blockIdx.x * 32;           // flat row in [0, BN)
    int b = row0g >> 12;
    int row0 = row0g & (N - 1);
    {
        const float4* src = reinterpret_cast<const float4*>(v + row0g * F);
        float4* dst = reinterpret_cast<float4*>(&vs[0][0]);
#pragma unroll
        for (int u = 0; u < 4; u++) dst[u * 256 + t] = src[u * 256 + t];
    }
    {
        const float4* src = reinterpret_cast<const float4*>(Wv_w);
#pragma unroll
        for (int u = 0; u < 16; u++) {
            int unit = u * 256 + t;
            int r = unit >> 5, s = unit & 31;
            float4 val = src[unit];
            Ws[r][s * 4 + 0] = val.x; Ws[r][s * 4 + 1] = val.y;
            Ws[r][s * 4 + 2] = val.z; Ws[r][s * 4 + 3] = val.w;
        }
    }
    int f = t & 127, g = t >> 7;
    float bias = Wv_b[f];
    __syncthreads();
    float acc[16];
#pragma unroll
    for (int r = 0; r < 16; r++) acc[r] = bias;
    for (int kk = 0; kk < F; kk++) {
        float wk = Ws[f][kk];
#pragma unroll
        for (int r = 0; r < 16; r++) acc[r] = fmaf(vs[g * 16 + r][kk], wk, acc[r]);
    }
#pragma unroll
    for (int r = 0; r < 16; r++) ts[f][g * 16 + r] = f2bf(acc[r]);
    __syncthreads();
    int fr = t >> 1, hseg = t & 1;
    uint4 d0 = *reinterpret_cast<uint4*>(&ts[fr][hseg * 16]);
    uint4 d1 = *reinterpret_cast<uint4*>(&ts[fr][hseg * 16 + 8]);
    unsigned short* dst = vpT + ((size_t)(b * F + fr) * N + row0 + hseg * 16);
    *reinterpret_cast<uint4*>(dst) = d0;
    *reinterpret_cast<uint4*>(dst + 8) = d1;
}

// ---------------- K3: MFMA attention, Mw=32, LDS-staged vpT, transposed bits ----------------
__global__ __launch_bounds__(256, 2) void k_attn(
    const unsigned short* __restrict__ vpT, const ull* __restrict__ packT,
    const float* __restrict__ Wh1, const float* __restrict__ P1, const float* __restrict__ Q1,
    const float* __restrict__ P2, const float* __restrict__ Q2, const float* __restrict__ Wh2,
    float* __restrict__ h_part, float* __restrict__ den_part) {
    __shared__ __align__(16) unsigned short bs[2][F][72];      // 36.9 KB dbuf, pad 72
    __shared__ __align__(16) float sP2[JC], sQ2[JC], sW2[JC];  // 12 KB
    int t = threadIdx.x;
    int idx = blockIdx.x;            // 512 = B * 32 i-tiles * 4 splits
    int split = idx & 3;
    int tile = (idx >> 2) & 31;
    int b = idx >> 7;
    int i0 = tile * 128;
    int jb0 = split * JC;
    int widx = t >> 6, lane = t & 63, m = lane & 15, q = lane >> 4;

    {  // preload P2/Q2/W2 tables for the whole j-slice
        reinterpret_cast<float4*>(sP2)[t] = reinterpret_cast<const float4*>(P2 + b * N + jb0)[t];
        reinterpret_cast<float4*>(sQ2)[t] = reinterpret_cast<const float4*>(Q2 + b * N + jb0)[t];
        reinterpret_cast<float4*>(sW2)[t] = reinterpret_cast<const float4*>(Wh2 + b * N + jb0)[t];
    }

    int gi0 = b * N + i0 + widx * 32 + m;   // rt=0 row of this lane
    int gi1 = gi0 + 16;                     // rt=1 row
    float p1a = P1[gi0], q1a = Q1[gi0], t1a = -Wh1[gi0];
    float p1b = P1[gi1], q1b = Q1[gi1], t1b = -Wh1[gi1];

    // transposed bits: word (b*64 + split*16 + it)*N + i ; lanes m coalesced, q broadcast
    const ull* pt = packT + ((size_t)b * 64 + (size_t)split * 16) * N + i0 + widx * 32 + m;
    const unsigned short* vb = vpT + (size_t)b * F * N + jb0;

    uint4 sreg[4];
    auto load_stage = [&](int it) {
#pragma unroll
        for (int u = 0; u < 4; u++) {
            int unit = u * 256 + t;
            int r = unit >> 3, s = unit & 7;
            sreg[u] = *reinterpret_cast<const uint4*>(vb + (size_t)r * N + it * BK + s * 8);
        }
    };
    auto write_stage = [&](int pb) {
#pragma unroll
        for (int u = 0; u < 4; u++) {
            int unit = u * 256 + t;
            int r = unit >> 3, s = unit & 7;
            *reinterpret_cast<uint4*>(&bs[pb][r][s * 8]) = sreg[u];
        }
    };

    float4v acc0[8], acc1[8];
#pragma unroll
    for (int nt = 0; nt < 8; nt++) {
        acc0[nt] = (float4v){0.f, 0.f, 0.f, 0.f};
        acc1[nt] = (float4v){0.f, 0.f, 0.f, 0.f};
    }
    float den0 = 0.f, den1 = 0.f;

    // w-gen from 8 adjacency bits -> bf16 A-frag
    auto gen_af = [&](unsigned bt, const float4& x2a, const float4& x2b,
                      const float4& p2a, const float4& p2b, const float4& q2a,
                      const float4& q2b, float p1, float q1, float t1, float& dn) -> short8 {
        float w0 = (bt & 1u)   ? ((x2a.x >= t1) ? p1 * p2a.x : q1 * q2a.x) : 0.f;
        float w1 = (bt & 2u)   ? ((x2a.y >= t1) ? p1 * p2a.y : q1 * q2a.y) : 0.f;
        float w2 = (bt & 4u)   ? ((x2a.z >= t1) ? p1 * p2a.z : q1 * q2a.z) : 0.f;
        float w3 = (bt & 8u)   ? ((x2a.w >= t1) ? p1 * p2a.w : q1 * q2a.w) : 0.f;
        float w4 = (bt & 16u)  ? ((x2b.x >= t1) ? p1 * p2b.x : q1 * q2b.x) : 0.f;
        float w5 = (bt & 32u)  ? ((x2b.y >= t1) ? p1 * p2b.y : q1 * q2b.y) : 0.f;
        float w6 = (bt & 64u)  ? ((x2b.z >= t1) ? p1 * p2b.z : q1 * q2b.z) : 0.f;
        float w7 = (bt & 128u) ? ((x2b.w >= t1) ? p1 * p2b.w : q1 * q2b.w) : 0.f;
        dn += ((w0 + w1) + (w2 + w3)) + ((w4 + w5) + (w6 + w7));
        union { short8 s; uint4 u; } r;
        r.u.x = pack_bf2(w0, w1); r.u.y = pack_bf2(w2, w3);
        r.u.z = pack_bf2(w4, w5); r.u.w = pack_bf2(w6, w7);
        return r.s;
    };

    auto body = [&](int it, int pb, ull pw0, ull pw1, ull& nx0, ull& nx1) {
        if (it + 1 < NIT) {  // prefetch next tile + bits (global->reg) under compute
            load_stage(it + 1);
            nx0 = pt[(size_t)(it + 1) * N];
            nx1 = pt[(size_t)(it + 1) * N + 16];
        }
#pragma unroll
        for (int kh = 0; kh < 2; kh++) {
            int jl = it * BK + kh * 32 + q * 8;
            float4 x2a = *reinterpret_cast<const float4*>(&sW2[jl]);
            float4 x2b = *reinterpret_cast<const float4*>(&sW2[jl + 4]);
            float4 p2a = *reinterpret_cast<const float4*>(&sP2[jl]);
            float4 p2b = *reinterpret_cast<const float4*>(&sP2[jl + 4]);
            float4 q2a = *reinterpret_cast<const float4*>(&sQ2[jl]);
            float4 q2b = *reinterpret_cast<const float4*>(&sQ2[jl + 4]);
            unsigned bt0 = ((unsigned)(pw0 >> (kh * 32)) >> (q * 8)) & 0xFFu;
            unsigned bt1 = ((unsigned)(pw1 >> (kh * 32)) >> (q * 8)) & 0xFFu;
            short8 af0 = gen_af(bt0, x2a, x2b, p2a, p2b, q2a, q2b, p1a, q1a, t1a, den0);
            short8 af1 = gen_af(bt1, x2a, x2b, p2a, p2b, q2a, q2b, p1b, q1b, t1b, den1);
#pragma unroll
            for (int nt = 0; nt < 8; nt++) {
                short8 bf = *reinterpret_cast<const short8*>(&bs[pb][nt * 16 + m][kh * 32 + q * 8]);
                acc0[nt] = __builtin_amdgcn_mfma_f32_16x16x32_bf16(af0, bf, acc0[nt], 0, 0, 0);
                acc1[nt] = __builtin_amdgcn_mfma_f32_16x16x32_bf16(af1, bf, acc1[nt], 0, 0, 0);
            }
        }
        if (it + 1 < NIT) write_stage(pb ^ 1);
        __syncthreads();
    };

    // prologue
    ull pwA0, pwA1, pwB0, pwB1;
    load_stage(0);
    pwA0 = pt[0];
    pwA1 = pt[16];
    write_stage(0);
    __syncthreads();   // covers table writes too

#pragma unroll 1
    for (int ith = 0; ith < NIT / 2; ith++) {
        body(ith * 2 + 0, 0, pwA0, pwA1, pwB0, pwB1);
        body(ith * 2 + 1, 1, pwB0, pwB1, pwA0, pwA1);
    }

    // epilogue: denominators (reduce over q) + partial numerators, plain stores
    den0 += __shfl_xor(den0, 16); den0 += __shfl_xor(den0, 32);
    den1 += __shfl_xor(den1, 16); den1 += __shfl_xor(den1, 32);
    float* dp = den_part + (size_t)split * BN;
    if (q == 0) { dp[gi0] = den0; dp[gi1] = den1; }
    float* hp = h_part + (size_t)split * BN * F;
    int orow = b * N + i0 + widx * 32 + q * 4;  // C/D: row = q*4+reg, col = m
#pragma unroll
    for (int nt = 0; nt < 8; nt++)
#pragma unroll
        for (int r = 0; r < 4; r++) {
            hp[(size_t)(orow + r) * F + nt * 16 + m] = acc0[nt][r];
            hp[(size_t)(orow + 16 + r) * F + nt * 16 + m] = acc1[nt][r];
        }
}

// ---------------- K4: out = leaky( ((sum_s h_s)/(sum_s den_s)) @ Wo^T ) ----------------
__global__ __launch_bounds__(256) void k_out(const float* __restrict__ h_part,
                                             const float* __restrict__ den_part,
                                             const float* __restrict__ Wo_w,
                                             float* __restrict__ out) {
    __shared__ float hs[32][F];    // 16 KB
    __shared__ float Ws[F][129];   // 66 KB
    int t = threadIdx.x;
    int row0 = blockIdx.x * 32;    // flat row in [0, BN)
    {
        const float4* src = reinterpret_cast<const float4*>(Wo_w);
#pragma unroll
        for (int u = 0; u < 16; u++) {
            int unit = u * 256 + t;
            int r = unit >> 5, s = unit & 31;
            float4 val = src[unit];
            Ws[r][s * 4 + 0] = val.x; Ws[r][s * 4 + 1] = val.y;
            Ws[r][s * 4 + 2] = val.z; Ws[r][s * 4 + 3] = val.w;
        }
    }
#pragma unroll
    for (int u = 0; u < 4; u++) {
        int unit = u * 256 + t;
        int r = unit >> 5, s = unit & 31;
        size_t off = (size_t)(row0 + r) * F + s * 4;
        float4 h0 = *reinterpret_cast<const float4*>(h_part + off);
        float4 h1 = *reinterpret_cast<const float4*>(h_part + (size_t)BN * F + off);
        float4 h2 = *reinterpret_cast<const float4*>(h_part + (size_t)2 * BN * F + off);
        float4 h3 = *reinterpret_cast<const float4*>(h_part + (size_t)3 * BN * F + off);
        float dsum = den_part[row0 + r] + den_part[BN + row0 + r] +
                     den_part[2 * BN + row0 + r] + den_part[3 * BN + row0 + r];
        float inv = 1.f / dsum;
        hs[r][s * 4 + 0] = (h0.x + h1.x + h2.x + h3.x) * inv;
        hs[r][s * 4 + 1] = (h0.y + h1.y + h2.y + h3.y) * inv;
        hs[r][s * 4 + 2] = (h0.z + h1.z + h2.z + h3.z) * inv;
        hs[r][s * 4 + 3] = (h0.w + h1.w + h2.w + h3.w) * inv;
    }
    __syncthreads();
    int f = t & 127, g = t >> 7;
    float acc[16];
#pragma unroll
    for (int r = 0; r < 16; r++) acc[r] = 0.f;
    for (int kk = 0; kk < F; kk++) {
        float wk = Ws[f][kk];
#pragma unroll
        for (int r = 0; r < 16; r++) acc[r] = fmaf(hs[g * 16 + r][kk], wk, acc[r]);
    }
#pragma unroll
    for (int r = 0; r < 16; r++) out[(size_t)(row0 + g * 16 + r) * F + f] = leaky(acc[r]);
}

extern "C" void kernel_launch(void* const* d_in, const int* in_sizes, int n_in,
                              void* d_out, int out_size, void* d_ws, size_t ws_size,
                              hipStream_t stream) {
    const float* q    = (const float*)d_in[0];
    const float* k    = (const float*)d_in[1];
    const float* v    = (const float*)d_in[2];
    const int*   adj  = (const int*)d_in[3];
    const float* Wq_w = (const float*)d_in[4];
    const float* Wq_b = (const float*)d_in[5];
    const float* Wk_w = (const float*)d_in[6];
    const float* Wk_b = (const float*)d_in[7];
    const float* Wv_w = (const float*)d_in[8];
    const float* Wv_b = (const float*)d_in[9];
    const float* a    = (const float*)d_in[10];
    const float* Wo_w = (const float*)d_in[11];
    float* out = (float*)d_out;
    float* ws = (float*)d_ws;

    unsigned short* vpT = (unsigned short*)ws;        // BN*F bf16 = BN*F/2 floats
    float* h_part   = ws + BN * F / 2;                // SPLITS*BN*F
    float* den_part = h_part + (size_t)SPLITS * BN * F;  // SPLITS*BN
    float* Wh1 = den_part + SPLITS * BN;
    float* Wh2 = Wh1 + BN;
    float* P1  = Wh2 + BN;
    float* Q1  = P1 + BN;
    float* P2  = Q1 + BN;
    float* Q2  = P2 + BN;
    float* c1  = Q2 + BN;                             // F
    float* c2  = c1 + F;                              // F
    float* d12 = c2 + F;                              // 2
    float* M2  = d12 + 2;                             // B
    size_t off = (size_t)((M2 + B) - ws);
    off = (off + 3) & ~(size_t)3;                     // 16-byte align
    ull* pack  = (ull*)(ws + off);                    // BN * (N/64) ull = 8 MB
    ull* packT = pack + (size_t)BN * (N / 64);        // 8 MB, transposed

    k_pack<<<2048, 256, 0, stream>>>(adj, pack);
    k_ptrans<<<B * 64, 256, 0, stream>>>(pack, packT);
    k_prep<<<1, 256, 0, stream>>>(Wq_w, Wq_b, Wk_w, Wk_b, a, c1, c2, d12);
    k_wh<<<BN / 8, 256, 0, stream>>>(q, k, c1, c2, d12, Wh1, Wh2);
    k_max2<<<B, 256, 0, stream>>>(Wh2, M2);
    k_tab<<<BN / 256, 256, 0, stream>>>(Wh1, Wh2, M2, P1, Q1, P2, Q2);
    k_vp<<<BN / 32, 256, 0, stream>>>(v, Wv_w, Wv_b, vpT);
    k_attn<<<B * 32 * SPLITS, 256, 0, stream>>>(vpT, packT, Wh1, P1, Q1, P2, Q2, Wh2,
                                                h_part, den_part);
    k_out<<<BN / 32, 256, 0, stream>>>(h_part, den_part, Wo_w, out);
}